// Round 1
// 57.328 us; speedup vs baseline: 1.2267x; 1.2267x over previous
//
#include <hip/hip_runtime.h>
#include <math.h>

#define NQ 12

// ===========================================================================
// Fully fused single kernel: out_v(x) = normalized |<e_v| U |s(x)>|^2.
//
// Previous version materialized M[k] = (U^dag e_v)[k] (4096 complex pairs,
// separate prep kernel) then contracted a dense 64x64 bilinear per batch
// (16k FMA/batch + 64KB LDS staging re-read by every wave).
//
// Key identity: U^dag e_b is a bond-4 MPS (prep's chain), and s(x) is a
// product state, so the contraction factorizes per qubit:
//   a_b(x) = sum_k v_b[k] prod_q s_q[k_q]
//          = sum_{j,i} prod_q [ sum_{kq} s_q[kq] G1_q[kq, j'^j] ]
//                             G2_q[j, i'^i] G3_q[i, b_q]
// Each k_q appears in exactly one chain factor, so the k-sum is just a
// (cos,sin)-blend of G1's two rows:
//   arr = c*g1.x - s*g1.z ; ari = c*g1.y + s*g1.w
//   brr = c*g1.z + s*g1.x ; bri = c*g1.w - s*g1.y
// Per batch: 12 transfer steps on a 4-dim bond vector (~150 FLOP each)
// instead of 16k FMA. One thread = one batch element; 8192 threads total.
// No M_dev, no prep dispatch, no 64KB LDS tile. d_ws untouched (the 256 MiB
// poison fill + reset-dispatch gaps are the dominant fixed harness cost).
// ===========================================================================

struct Gate { float g00r, g00i, g01r, g01i; };

__device__ __forceinline__ Gate make_gate(const float* __restrict__ params,
                                          int layer, int q) {
  float p0 = params[(layer*NQ + q)*3 + 0];
  float p1 = params[(layer*NQ + q)*3 + 1];
  float p2 = params[(layer*NQ + q)*3 + 2];
  float s0, c0, s1, c1, sz, cz;
  __sincosf(0.5f*p0, &s0, &c0);
  __sincosf(0.5f*p1, &s1, &c1);
  __sincosf(0.5f*p2, &sz, &cz);
  float ur = c0*c1, ui = s0*s1, wr = s0*c1, wi = c0*s1;
  Gate g;
  g.g00r = cz*ur - sz*ui;  g.g00i = cz*ui + sz*ur;
  g.g01r = cz*wr + sz*wi;  g.g01i = cz*wi - sz*wr;
  return g;
}

// 128 blocks x 64 threads: thread -> one batch element.
__global__ __launch_bounds__(64) void qnn_fused(const float* __restrict__ x,
                                                const float* __restrict__ params,
                                                float* __restrict__ out,
                                                int nbatch) {
  __shared__ float4 gtab[36];                  // idx = layer*12 + q
  const int tid = threadIdx.x;
  if (tid < 36) {
    Gate g = make_gate(params, tid / 12, tid % 12);
    gtab[tid] = make_float4(g.g00r, g.g00i, g.g01r, g.g01i);
  }
  __syncthreads();

  const int batch = blockIdx.x * 64 + tid;
  int bb = batch < nbatch ? batch : nbatch - 1;

  // 12 contiguous floats per batch, 48B stride -> 16B aligned float4 loads
  const float4* xv = (const float4*)(x + (size_t)bb * NQ);
  float4 xa = xv[0], xm = xv[1], xz = xv[2];
  float xs[12] = {xa.x, xa.y, xa.z, xa.w, xm.x, xm.y, xm.z, xm.w,
                  xz.x, xz.y, xz.z, xz.w};
  float cq[12], sq[12];
#pragma unroll
  for (int q = 0; q < 12; ++q) __sincosf(0.5f * xs[q], &sq[q], &cq[q]);

  // bond vector u[(j,i)] = u[j*2+i], start at (0,0)
  float ur[4] = {1.f, 0.f, 0.f, 0.f};
  float ui[4] = {0.f, 0.f, 0.f, 0.f};

#pragma unroll
  for (int q = 0; q < 11; ++q) {
    float4 g1 = gtab[q];                       // R1 layer (params layer 0)
    float4 g2 = gtab[12 + q];                  // R2 layer (params layer 1)
    float4 g3 = gtab[24 + q];                  // R3 layer (params layer 2)
    const float c = cq[q], s = sq[q];

    // k-contracted (blended) G1 row: c*G1[0,:] + s*G1[1,:]
    float arr = c*g1.x - s*g1.z,  ari = c*g1.y + s*g1.w;
    float brr = c*g1.z + s*g1.x,  bri = c*g1.w - s*g1.y;

    // step1 (contract old j): t[jn,i] = u[0,i]*A(jn) + u[1,i]*A(1^jn)
    float tr[4], ti[4];
#pragma unroll
    for (int i = 0; i < 2; ++i) {
      float u0r = ur[i],     u0i = ui[i];      // (j=0, i)
      float u1r = ur[2 + i], u1i = ui[2 + i];  // (j=1, i)
      tr[i]     = u0r*arr - u0i*ari + u1r*brr - u1i*bri;   // jn=0
      ti[i]     = u0r*ari + u0i*arr + u1r*bri + u1i*brr;
      tr[2 + i] = u0r*brr - u0i*bri + u1r*arr - u1i*ari;   // jn=1
      ti[2 + i] = u0r*bri + u0i*brr + u1r*ari + u1i*arr;
    }
    // step2 (contract old i): u'[j,in] = G3[in,0] * sum_i t[j,i] G2[j, i^in]
    float A0r = g3.x, A0i = g3.y;              // G3[0,0]  (bq=0 for q<11)
    float A1r = -g3.z, A1i = g3.w;             // G3[1,0]
#pragma unroll
    for (int j = 0; j < 2; ++j) {
      float cjr = j ? -g2.z : g2.x, cji = j ?  g2.w : g2.y;  // G2[j,0]
      float djr = j ?  g2.x : g2.z, dji = j ? -g2.y : g2.w;  // G2[j,1]
      float t0r = tr[j*2], t0i = ti[j*2], t1r = tr[j*2+1], t1i = ti[j*2+1];
      float w0r = t0r*cjr - t0i*cji + t1r*djr - t1i*dji;
      float w0i = t0r*cji + t0i*cjr + t1r*dji + t1i*djr;
      float w1r = t0r*djr - t0i*dji + t1r*cjr - t1i*cji;
      float w1i = t0r*dji + t0i*djr + t1r*cji + t1i*cjr;
      ur[j*2]   = A0r*w0r - A0i*w0i;  ui[j*2]   = A0r*w0i + A0i*w0r;
      ur[j*2+1] = A1r*w1r - A1i*w1i;  ui[j*2+1] = A1r*w1i + A1i*w1r;
    }
  }

  // tail qubit 11: step1 + step2's w, then close both chains (b=0 and b=1).
  // close(b) = sum_j [ G3[0,b]*w[j][0] + G3[1,b]*w[j][1] ] = A0(b)*W0 + A1(b)*W1
  {
    float4 g1 = gtab[11], g2 = gtab[23], g3 = gtab[35];
    const float c = cq[11], s = sq[11];
    float arr = c*g1.x - s*g1.z,  ari = c*g1.y + s*g1.w;
    float brr = c*g1.z + s*g1.x,  bri = c*g1.w - s*g1.y;
    float tr[4], ti[4];
#pragma unroll
    for (int i = 0; i < 2; ++i) {
      float u0r = ur[i],     u0i = ui[i];
      float u1r = ur[2 + i], u1i = ui[2 + i];
      tr[i]     = u0r*arr - u0i*ari + u1r*brr - u1i*bri;
      ti[i]     = u0r*ari + u0i*arr + u1r*bri + u1i*brr;
      tr[2 + i] = u0r*brr - u0i*bri + u1r*arr - u1i*ari;
      ti[2 + i] = u0r*bri + u0i*brr + u1r*ari + u1i*arr;
    }
    float W0r = 0.f, W0i = 0.f, W1r = 0.f, W1i = 0.f;
#pragma unroll
    for (int j = 0; j < 2; ++j) {
      float cjr = j ? -g2.z : g2.x, cji = j ?  g2.w : g2.y;
      float djr = j ?  g2.x : g2.z, dji = j ? -g2.y : g2.w;
      float t0r = tr[j*2], t0i = ti[j*2], t1r = tr[j*2+1], t1i = ti[j*2+1];
      W0r += t0r*cjr - t0i*cji + t1r*djr - t1i*dji;
      W0i += t0r*cji + t0i*cjr + t1r*dji + t1i*djr;
      W1r += t0r*djr - t0i*dji + t1r*cjr - t1i*cji;
      W1i += t0r*dji + t0i*djr + t1r*cji + t1i*cjr;
    }
    // b=0: A0=(g3.x,g3.y), A1=(-g3.z,g3.w)
    float a0r = g3.x*W0r - g3.y*W0i - g3.z*W1r - g3.w*W1i;
    float a0i = g3.x*W0i + g3.y*W0r - g3.z*W1i + g3.w*W1r;
    // b=1: A0=(g3.z,g3.w), A1=(g3.x,-g3.y)
    float a1r = g3.z*W0r - g3.w*W0i + g3.x*W1r + g3.y*W1i;
    float a1i = g3.z*W0i + g3.w*W0r + g3.x*W1i - g3.y*W1r;

    float p0 = a0r*a0r + a0i*a0i;
    float p1 = a1r*a1r + a1i*a1i;
    float inv = 1.0f / (p0 + p1);
    if (batch < nbatch)
      ((float2*)out)[batch] = make_float2(p0 * inv, p1 * inv);
  }
}

extern "C" void kernel_launch(void* const* d_in, const int* in_sizes, int n_in,
                              void* d_out, int out_size, void* d_ws, size_t ws_size,
                              hipStream_t stream) {
  const float* x      = (const float*)d_in[0];
  const float* params = (const float*)d_in[1];
  float* out = (float*)d_out;
  (void)d_ws; (void)ws_size;                   // deliberately unused

  const int nbatch = in_sizes[0] / NQ;         // 8192
  qnn_fused<<<(nbatch + 63) / 64, 64, 0, stream>>>(x, params, out, nbatch);
}